// Round 1
// baseline (229.390 us; speedup 1.0000x reference)
//
#include <hip/hip_runtime.h>
#include <hip/hip_bf16.h>
#include <cstddef>

#define G_   2048
#define NPG_ 512
#define CPG_ 128
#define CPG2_ 32

// output layout (floats): z_what[G,64] | z_mask[G,64] | mu[G,128] | sigma[G,128] | f[G,256]
#define OFF_ZW 0
#define OFF_ZM (G_*64)
#define OFF_MU (2*G_*64)
#define OFF_SG (2*G_*64 + G_*128)
#define OFF_F  (2*G_*64 + 2*G_*128)

typedef __attribute__((ext_vector_type(8))) short bf16x8;
typedef __attribute__((ext_vector_type(4))) float f32x4;

__device__ __forceinline__ float celu_f(float x)     { return x > 0.f ? x : __expf(x) - 1.f; }
__device__ __forceinline__ float softplus_f(float x) { return fmaxf(x, 0.f) + __logf(1.f + __expf(-fabsf(x))); }
// fast RNE fp32->bf16 (finite inputs): identical result to __float2bfloat16
__device__ __forceinline__ unsigned short f2bf(float x) {
    unsigned u = __float_as_uint(x);
    u += 0x7FFFu + ((u >> 16) & 1u);
    return (unsigned short)(u >> 16);
}
__device__ __forceinline__ unsigned pack2(float a, float b) {   // bf16(a) | bf16(b)<<16
    unsigned ua = __float_as_uint(a); ua += 0x7FFFu + ((ua >> 16) & 1u);
    unsigned ub = __float_as_uint(b); ub += 0x7FFFu + ((ub >> 16) & 1u);
    return (ua >> 16) | (ub & 0xFFFF0000u);
}
// 8B-aligned bf16x8 LDS load (for stride-132 rows)
__device__ __forceinline__ bf16x8 ldb8(const unsigned short* p) {
    union { uint2 u[2]; bf16x8 v; } x;
    x.u[0] = *(const uint2*)p;
    x.u[1] = *(const uint2*)(p + 4);
    return x.v;
}

// ---------------- prep: transposed, zero-K-padded bf16 weight copies in ws ----------------
__global__ void k_prep(const float* __restrict__ W2l, const float* __restrict__ W2g,
                       const float* __restrict__ W3l, const float* __restrict__ W3g,
                       const float* __restrict__ Wlin, const float* __restrict__ W1g,
                       unsigned short* __restrict__ w2lT, unsigned short* __restrict__ w2gT,
                       unsigned short* __restrict__ w3lT, unsigned short* __restrict__ w3gT,
                       unsigned short* __restrict__ wlinT, unsigned short* __restrict__ w1gT)
{
    const int tid = blockIdx.x*256 + threadIdx.x, stride = gridDim.x*256;
    for (int i = tid; i < 64*64; i += stride) {          // W2l [35,64] -> [ch][k=64pad]
        const int ch = i >> 6, k = i & 63;
        w2lT[i] = f2bf(k < 35 ? W2l[k*64 + ch] : 0.f);
    }
    for (int i = tid; i < 128*64; i += stride) {         // W2g [64,128] -> [ch][k]
        const int ch = i >> 6, k = i & 63;
        w2gT[i] = f2bf(W2g[k*128 + ch]);
    }
    for (int i = tid; i < 128*160; i += stride) {        // W3l [131,128] -> [ch][k=160pad]
        const int ch = i / 160, k = i % 160;
        w3lT[i] = f2bf(k < 131 ? W3l[k*128 + ch] : 0.f);
    }
    for (int i = tid; i < 256*128; i += stride) {        // W3g [128,256] -> [ch][k]
        const int ch = i >> 7, k = i & 127;
        w3gT[i] = f2bf(W3g[k*256 + ch]);
    }
    for (int i = tid; i < 256*256; i += stride) {        // Wlin [256,256] -> [ch][k]
        const int ch = i >> 8, k = i & 255;
        wlinT[i] = f2bf(Wlin[k*256 + ch]);
    }
    for (int i = tid; i < 32*40; i += stride) {          // W1g [16,32] -> [ch][k=40pad]
        const int ch = i / 40, k = i % 40;
        w1gT[i] = f2bf(k < 16 ? W1g[k*32 + ch] : 0.f);
    }
}

// ============== fused conv1+conv2+conv3local+mean: one block per glimpse ==============
// LDS 27008 B (rounds to 27136 -> 6 blocks/CU), phase overlays:
//  Region1 [0,18432):   aggf f32[16][128] @0 + aggT us[128][40] @8192 (conv1)
//                       -> xs16 us[128][72] -> HT us[64][136] -> xs3 us[32][168]
//  Region2 [18432,26880): cntf f32[128] + cntif f32[32] (conv1, dead by B3)
//                       -> sT us[32][132] -> agg2 us[32][72] -> red f32[128][9]
//  invc f32[32] @26880
// conv1 front-end: direct LDS f32 atomic segment-sum (ds_add_f32, bank = c mod 32)
// replaces count->scan->scatter->serial-accumulate (saves 3 barriers + divergent loop).
__global__ __launch_bounds__(256, 6) void k_fused(
    const float* __restrict__ rgb, const float* __restrict__ pos, const float* __restrict__ pos1,
    const float* __restrict__ pos2, const int* __restrict__ idx0, const int* __restrict__ idx1,
    const float* __restrict__ W1l, const float* __restrict__ b1l,
    const unsigned short* __restrict__ w1gT, const float* __restrict__ b1g,
    const unsigned short* __restrict__ w2lT, const float* __restrict__ b2l,
    const unsigned short* __restrict__ w2gT, const float* __restrict__ b2g,
    const unsigned short* __restrict__ w3lT, const float* __restrict__ b3l,
    unsigned short* __restrict__ aggws)
{
    const int g = blockIdx.x, t = threadIdx.x;
    const int lane = t & 63, wv = t >> 6;
    const int lr = lane & 15, quad = lane >> 4;

    __shared__ __align__(16) unsigned char smem[27008];
    float* const aggf = (float*)smem;                              // [16][128] f32 (transposed: bank = c&31)
    unsigned short* const aggT = (unsigned short*)(smem + 8192);   // [128][40]
    unsigned short* const xs16 = (unsigned short*)smem;            // [128][72]
    unsigned short* const HT   = (unsigned short*)smem;            // [64][136]
    unsigned short* const xs3  = (unsigned short*)smem;            // [32][168]
    float* const cntf  = (float*)(smem + 18432);                   // [128]
    float* const cntif = (float*)(smem + 18944);                   // [32]
    unsigned short* const sT   = (unsigned short*)(smem + 18432);  // [32][132]
    unsigned short* const agg2 = (unsigned short*)(smem + 18432);  // [32][72]
    float* const red  = (float*)(smem + 18432);                    // [128][9]
    float* const invc = (float*)(smem + 26880);                    // [32]

    // ---- pre-B0: zero aggf/counters, slc/rel into regs, zero aggT K-pad cols 16..31 ----
    if (t < CPG_)  cntf[t]  = 0.f;
    if (t < CPG2_) cntif[t] = 0.f;
    {
        const uint4 z4 = {0u, 0u, 0u, 0u};
        ((uint4*)aggf)[t]       = z4;       // 8192 B = 512 uint4
        ((uint4*)aggf)[256 + t] = z4;
    }
    int slc_r = 0;
    float relx = 0.f, rely = 0.f, relz = 0.f;
    if (t < CPG_) {
        const int c2 = idx1[g*CPG_ + t];
        slc_r = c2 - g*CPG2_;
        relx = pos1[(g*CPG_ + t)*3 + 0] - pos2[c2*3 + 0];
        rely = pos1[(g*CPG_ + t)*3 + 1] - pos2[c2*3 + 1];
        relz = pos1[(g*CPG_ + t)*3 + 2] - pos2[c2*3 + 2];
    }
    for (int i = t; i < 128*8; i += 256) {
        const int r = i >> 3, j = i & 7;
        ((unsigned*)aggT)[r*20 + 8 + j] = 0u;
    }
    __syncthreads();   // B0

    // ---- conv1 local: per-edge MLP in f32 + LDS atomic segment-sum ----
    {
        float px0[2], prx[2], pry[2], prz[2];
        int plc[2];
        #pragma unroll
        for (int r = 0; r < 2; r++) {
            const int lp = r*256 + t;
            const int p  = g*NPG_ + lp;
            const int c  = idx0[p];
            plc[r] = c - g*CPG_;
            px0[r] = rgb[p];
            prx[r] = pos[p*3+0] - pos1[c*3+0];
            pry[r] = pos[p*3+1] - pos1[c*3+1];
            prz[r] = pos[p*3+2] - pos1[c*3+2];
        }
        atomicAdd(&cntf[plc[0]], 1.f);
        atomicAdd(&cntf[plc[1]], 1.f);
        if (t < CPG_) atomicAdd(&cntif[slc_r], 1.f);
        #pragma unroll
        for (int j = 0; j < 16; j++) {
            const float wj = W1l[j], wx = W1l[16+j], wy = W1l[32+j], wz = W1l[48+j];
            const float bb = b1l[j];
            const float h0 = bb + px0[0]*wj + prx[0]*wx + pry[0]*wy + prz[0]*wz;
            const float h1 = bb + px0[1]*wj + prx[1]*wx + pry[1]*wy + prz[1]*wz;
            atomicAdd(&aggf[j*128 + plc[0]], celu_f(h0));
            atomicAdd(&aggf[j*128 + plc[1]], celu_f(h1));
        }
    }
    __syncthreads();   // B1

    // ---- normalize -> aggT bf16 cols 0..15 (2 threads/cluster) ----
    {
        const int c = t >> 1, ch0 = (t & 1) * 8;
        const float inv = 1.f / fmaxf(cntf[c], 1.f);
        float a[8];
        #pragma unroll
        for (int j = 0; j < 8; j++) a[j] = aggf[(ch0 + j)*128 + c] * inv;
        uint2 q0, q1;
        q0.x = pack2(a[0], a[1]);
        q0.y = pack2(a[2], a[3]);
        q1.x = pack2(a[4], a[5]);
        q1.y = pack2(a[6], a[7]);
        *(uint2*)&aggT[c*40 + ch0]     = q0;
        *(uint2*)&aggT[c*40 + ch0 + 4] = q1;
    }
    if (t < CPG2_) invc[t] = 1.f / fmaxf(cntif[t], 1.f);
    __syncthreads();   // B2

    // ---- conv1 global conv MFMA: [128,32(K pad)] @ w1gT -> C regs ----
    f32x4 c1[2][2];    // [nt][mt]
    {
        #pragma unroll
        for (int nt = 0; nt < 2; nt++) {
            const float bias = b1g[nt*16 + lr];
            c1[nt][0] = (f32x4){bias, bias, bias, bias};
            c1[nt][1] = (f32x4){bias, bias, bias, bias};
        }
        const bf16x8 b0 = *(const bf16x8*)&w1gT[(0*16 + lr)*40 + quad*8];
        const bf16x8 b1 = *(const bf16x8*)&w1gT[(1*16 + lr)*40 + quad*8];
        #pragma unroll
        for (int mt = 0; mt < 2; mt++) {
            const bf16x8 a = *(const bf16x8*)&aggT[((2*wv + mt)*16 + lr)*40 + quad*8];
            c1[0][mt] = __builtin_amdgcn_mfma_f32_16x16x32_bf16(a, b0, c1[0][mt], 0, 0, 0);
            c1[1][mt] = __builtin_amdgcn_mfma_f32_16x16x32_bf16(a, b1, c1[1][mt], 0, 0, 0);
        }
    }
    __syncthreads();   // B3 (aggf/aggT dead -> xs16; cntf/cntif dead -> sT)

    // ---- zero sT; write f1 into xs16 cols 0..31, relpos 32..34, zero 35..63 ----
    {
        const uint4 z4 = {0u, 0u, 0u, 0u};
        for (int i = t; i < 528; i += 256) ((uint4*)sT)[i] = z4;   // 32*132 us = 8448 B
    }
    #pragma unroll
    for (int nt = 0; nt < 2; nt++)
    #pragma unroll
    for (int mt = 0; mt < 2; mt++)
    #pragma unroll
    for (int r = 0; r < 4; r++) {
        const int cl = (2*wv + mt)*16 + quad*4 + r;
        xs16[cl*72 + nt*16 + lr] = f2bf(celu_f(c1[nt][mt][r]));
    }
    if (t < CPG_) {
        xs16[t*72 + 32] = f2bf(relx);
        xs16[t*72 + 33] = f2bf(rely);
        xs16[t*72 + 34] = f2bf(relz);
    }
    for (int i = t; i < 128*29; i += 256) {
        const int r = i / 29, c = 35 + (i - r*29);
        xs16[r*72 + c] = 0;
    }
    __syncthreads();   // B4

    // ---- one-hot scatter into sT; conv2 local MFMA (reads xs16) ----
    if (t < CPG_) sT[slc_r*132 + t] = 0x3F80;   // bf16 1.0
    float hv[8][4];
    {
        const int chn = wv*16 + lr;
        const bf16x8 bw0 = *(const bf16x8*)&w2lT[chn*64 + quad*8];
        const bf16x8 bw1 = *(const bf16x8*)&w2lT[chn*64 + 32 + quad*8];
        const float bias = b2l[chn];
        #pragma unroll
        for (int m = 0; m < 8; m++) {
            f32x4 acc = (f32x4){bias, bias, bias, bias};
            const bf16x8 a0 = *(const bf16x8*)&xs16[(m*16 + lr)*72 + quad*8];
            const bf16x8 a1 = *(const bf16x8*)&xs16[(m*16 + lr)*72 + 32 + quad*8];
            acc = __builtin_amdgcn_mfma_f32_16x16x32_bf16(a0, bw0, acc, 0, 0, 0);
            acc = __builtin_amdgcn_mfma_f32_16x16x32_bf16(a1, bw1, acc, 0, 0, 0);
            #pragma unroll
            for (int r = 0; r < 4; r++) hv[m][r] = celu_f(acc[r]);
        }
    }
    __syncthreads();   // B5 (xs16 dead -> HT)

    // ---- store H^T ----
    {
        const int chn = wv*16 + lr;
        #pragma unroll
        for (int m = 0; m < 8; m++) {
            uint2 p;
            p.x = pack2(hv[m][0], hv[m][1]);
            p.y = pack2(hv[m][2], hv[m][3]);
            *(uint2*)&HT[chn*136 + m*16 + quad*4] = p;
        }
    }
    __syncthreads();   // B6

    // ---- segment-sum MFMA agg[32][64] = S^T @ H (sT rows 8B-aligned -> ldb8) ----
    float aggv[2][4];
    {
        const int ch = wv*16 + lr;
        f32x4 acc[2];
        acc[0] = (f32x4){0.f, 0.f, 0.f, 0.f};
        acc[1] = (f32x4){0.f, 0.f, 0.f, 0.f};
        #pragma unroll
        for (int ks = 0; ks < 4; ks++) {
            const bf16x8 b = *(const bf16x8*)&HT[ch*136 + ks*32 + quad*8];
            #pragma unroll
            for (int mt = 0; mt < 2; mt++) {
                const bf16x8 a = ldb8(&sT[(mt*16 + lr)*132 + ks*32 + quad*8]);
                acc[mt] = __builtin_amdgcn_mfma_f32_16x16x32_bf16(a, b, acc[mt], 0, 0, 0);
            }
        }
        #pragma unroll
        for (int mt = 0; mt < 2; mt++)
        #pragma unroll
        for (int r = 0; r < 4; r++)
            aggv[mt][r] = acc[mt][r] * invc[mt*16 + quad*4 + r];
    }
    __syncthreads();   // B7 (sT dead -> agg2; HT dead -> xs3)

    // ---- agg2 stores (Region2) + xs3 pads/zeros (Region1) ----
    {
        const int ch = wv*16 + lr;
        #pragma unroll
        for (int mt = 0; mt < 2; mt++)
        #pragma unroll
        for (int r = 0; r < 4; r++)
            agg2[(mt*16 + quad*4 + r)*72 + ch] = f2bf(aggv[mt][r]);
    }
    if (t < CPG2_) {
        #pragma unroll
        for (int d = 0; d < 3; d++)
            xs3[t*168 + 128 + d] = f2bf(pos2[(g*CPG2_ + t)*3 + d]);
    }
    for (int i = t; i < 32*29; i += 256) {
        const int r = i / 29, c = 131 + (i - r*29);
        xs3[r*168 + c] = 0;
    }
    __syncthreads();   // B8

    // ---- conv2 global MFMA -> f2 bf16 into xs3 cols 0..127 ----
    {
        f32x4 acc2[2][2];
        int   chn2[2];
        bf16x8 bw[2][2];
        #pragma unroll
        for (int nt = 0; nt < 2; nt++) {
            chn2[nt] = (wv + nt*4)*16 + lr;
            const float bias = b2g[chn2[nt]];
            #pragma unroll
            for (int mt = 0; mt < 2; mt++) acc2[nt][mt] = (f32x4){bias, bias, bias, bias};
            bw[nt][0] = *(const bf16x8*)&w2gT[chn2[nt]*64 + quad*8];
            bw[nt][1] = *(const bf16x8*)&w2gT[chn2[nt]*64 + 32 + quad*8];
        }
        #pragma unroll
        for (int ks = 0; ks < 2; ks++) {
            #pragma unroll
            for (int mt = 0; mt < 2; mt++) {
                const bf16x8 a = *(const bf16x8*)&agg2[(mt*16 + lr)*72 + ks*32 + quad*8];
                acc2[0][mt] = __builtin_amdgcn_mfma_f32_16x16x32_bf16(a, bw[0][ks], acc2[0][mt], 0, 0, 0);
                acc2[1][mt] = __builtin_amdgcn_mfma_f32_16x16x32_bf16(a, bw[1][ks], acc2[1][mt], 0, 0, 0);
            }
        }
        #pragma unroll
        for (int nt = 0; nt < 2; nt++)
        #pragma unroll
        for (int mt = 0; mt < 2; mt++)
        #pragma unroll
        for (int r = 0; r < 4; r++) {
            const int row = mt*16 + quad*4 + r;
            xs3[row*168 + chn2[nt]] = f2bf(celu_f(acc2[nt][mt][r]));
        }
    }
    __syncthreads();   // B9 (agg2 dead -> red)

    // ---- conv3 local MFMA (M=32) -> celu -> partials -> red ----
    {
        f32x4 acc[2][2];
        int chn[2];
        #pragma unroll
        for (int nt = 0; nt < 2; nt++) {
            chn[nt] = (wv + nt*4)*16 + lr;
            const float bias = b3l[chn[nt]];
            #pragma unroll
            for (int mt = 0; mt < 2; mt++) acc[nt][mt] = (f32x4){bias, bias, bias, bias};
        }
        #pragma unroll
        for (int ks = 0; ks < 5; ks++) {
            const bf16x8 b0 = *(const bf16x8*)&w3lT[chn[0]*160 + ks*32 + quad*8];
            const bf16x8 b1 = *(const bf16x8*)&w3lT[chn[1]*160 + ks*32 + quad*8];
            #pragma unroll
            for (int mt = 0; mt < 2; mt++) {
                const bf16x8 a = *(const bf16x8*)&xs3[(mt*16 + lr)*168 + ks*32 + quad*8];
                acc[0][mt] = __builtin_amdgcn_mfma_f32_16x16x32_bf16(a, b0, acc[0][mt], 0, 0, 0);
                acc[1][mt] = __builtin_amdgcn_mfma_f32_16x16x32_bf16(a, b1, acc[1][mt], 0, 0, 0);
            }
        }
        #pragma unroll
        for (int nt = 0; nt < 2; nt++)
        #pragma unroll
        for (int mt = 0; mt < 2; mt++) {
            const float p = celu_f(acc[nt][mt][0]) + celu_f(acc[nt][mt][1])
                          + celu_f(acc[nt][mt][2]) + celu_f(acc[nt][mt][3]);
            red[chn[nt]*9 + mt*4 + quad] = p;
        }
    }
    __syncthreads();   // B10

    // ---- mean -> aggws bf16 ----
    if (t < 128) {
        const float* rp = &red[t*9];
        float a = 0.f;
        #pragma unroll
        for (int p = 0; p < 8; p++) a += rp[p];
        aggws[(size_t)g*128 + t] = f2bf(a * (1.f/32.f));
    }
}

// ============== head: 16 glimpses per block; z/mu/sigma from paired accumulators ==============
__global__ __launch_bounds__(256) void k_head(
    const unsigned short* __restrict__ aggws,
    const unsigned short* __restrict__ w3gT, const float* __restrict__ b3g,
    const unsigned short* __restrict__ wlinT, const float* __restrict__ blin,
    const float* __restrict__ eps, float* __restrict__ out)
{
    const int g0 = blockIdx.x * 16, t = threadIdx.x;
    const int lane = t & 63, wv = t >> 6;
    const int lr = lane & 15, quad = lane >> 4;
    __shared__ __align__(16) unsigned short aggB[16*136];
    __shared__ __align__(16) unsigned short f3B[16*264];

    {   // stage agg rows: 256 uint4
        const int row = t >> 4, col8 = (t & 15) * 8;
        const uint4 v = ((const uint4*)aggws)[(size_t)g0*16 + t];
        *(uint4*)&aggB[row*136 + col8] = v;
    }
    __syncthreads();

    // W3g MFMA: C[16 glimpses][256] = aggB @ W3g
    {
        f32x4 c3[4];
        int ch3[4];
        #pragma unroll
        for (int nt = 0; nt < 4; nt++) {
            ch3[nt] = (wv + nt*4)*16 + lr;
            const float bias = b3g[ch3[nt]];
            c3[nt] = (f32x4){bias, bias, bias, bias};
        }
        #pragma unroll
        for (int ks = 0; ks < 4; ks++) {
            const bf16x8 a = *(const bf16x8*)&aggB[lr*136 + ks*32 + quad*8];
            #pragma unroll
            for (int nt = 0; nt < 4; nt++) {
                const bf16x8 b = *(const bf16x8*)&w3gT[ch3[nt]*128 + ks*32 + quad*8];
                c3[nt] = __builtin_amdgcn_mfma_f32_16x16x32_bf16(a, b, c3[nt], 0, 0, 0);
            }
        }
        #pragma unroll
        for (int nt = 0; nt < 4; nt++)
        #pragma unroll
        for (int r = 0; r < 4; r++) {
            const int row = quad*4 + r;
            const float v = celu_f(c3[nt][r]);
            out[OFF_F + (size_t)(g0 + row)*256 + ch3[nt]] = v;
            f3B[row*264 + ch3[nt]] = f2bf(v);
        }
    }
    __syncthreads();

    // Wlin MFMA: C[16][256] = f3B @ Wlin; sample in-register (lane owns ch and ch+128)
    {
        f32x4 cl[4];
        int ch4[4];
        #pragma unroll
        for (int nt = 0; nt < 4; nt++) {
            ch4[nt] = (wv + nt*4)*16 + lr;
            const float bias = blin[ch4[nt]];
            cl[nt] = (f32x4){bias, bias, bias, bias};
        }
        #pragma unroll
        for (int ks = 0; ks < 8; ks++) {
            const bf16x8 a = *(const bf16x8*)&f3B[lr*264 + ks*32 + quad*8];
            #pragma unroll
            for (int nt = 0; nt < 4; nt++) {
                const bf16x8 b = *(const bf16x8*)&wlinT[ch4[nt]*256 + ks*32 + quad*8];
                cl[nt] = __builtin_amdgcn_mfma_f32_16x16x32_bf16(a, b, cl[nt], 0, 0, 0);
            }
        }
        // nt and nt+2 share the lane: ch4[nt+2] == ch4[nt] + 128
        #pragma unroll
        for (int nt = 0; nt < 2; nt++)
        #pragma unroll
        for (int r = 0; r < 4; r++) {
            const int row = quad*4 + r;
            const int g = g0 + row;
            const int ch = ch4[nt];                 // 0..127
            const float mu    = cl[nt][r];
            const float sigma = softplus_f(cl[nt + 2][r]);
            const float z     = mu + sigma * eps[(size_t)g*128 + ch];
            out[OFF_MU + (size_t)g*128 + ch] = mu;
            out[OFF_SG + (size_t)g*128 + ch] = sigma;
            if (nt == 0) out[OFF_ZW + (size_t)g*64 + ch] = z;          // ch in [0,64)
            else         out[OFF_ZM + (size_t)g*64 + (ch - 64)] = z;   // ch in [64,128)
        }
    }
}

extern "C" void kernel_launch(void* const* d_in, const int* in_sizes, int n_in,
                              void* d_out, int out_size, void* d_ws, size_t ws_size,
                              hipStream_t stream)
{
    const float* rgb  = (const float*)d_in[0];
    const float* pos  = (const float*)d_in[1];
    const float* pos1 = (const float*)d_in[2];
    const float* pos2 = (const float*)d_in[3];
    const int*   idx0 = (const int*)d_in[4];
    const int*   idx1 = (const int*)d_in[5];
    const float* eps  = (const float*)d_in[7];
    const float* W1l = (const float*)d_in[8],  *b1l = (const float*)d_in[9];
    const float* W1g = (const float*)d_in[10], *b1g = (const float*)d_in[11];
    const float* W2l = (const float*)d_in[12], *b2l = (const float*)d_in[13];
    const float* W2g = (const float*)d_in[14], *b2g = (const float*)d_in[15];
    const float* W3l = (const float*)d_in[16], *b3l = (const float*)d_in[17];
    const float* W3g = (const float*)d_in[18], *b3g = (const float*)d_in[19];
    const float* Wlin = (const float*)d_in[20], *blin = (const float*)d_in[21];

    unsigned short* w2lT  = (unsigned short*)d_ws;       // 64*64
    unsigned short* w2gT  = w2lT + 64*64;                // 128*64
    unsigned short* w3lT  = w2gT + 128*64;               // 128*160
    unsigned short* w3gT  = w3lT + 128*160;              // 256*128
    unsigned short* wlinT = w3gT + 256*128;              // 256*256
    unsigned short* w1gT  = wlinT + 256*256;             // 32*40
    unsigned short* aggws = w1gT + 32*40;                // G*128 bf16
    float* outp = (float*)d_out;

    k_prep <<<64,    256, 0, stream>>>(W2l, W2g, W3l, W3g, Wlin, W1g,
                                       w2lT, w2gT, w3lT, w3gT, wlinT, w1gT);
    k_fused<<<G_,    256, 0, stream>>>(rgb, pos, pos1, pos2, idx0, idx1,
                                       W1l, b1l, w1gT, b1g,
                                       w2lT, b2l, w2gT, b2g, w3lT, b3l, aggws);
    k_head <<<G_/16, 256, 0, stream>>>(aggws, w3gT, b3g, wlinT, blin, eps, outp);
}

// Round 2
// 168.468 us; speedup vs baseline: 1.3616x; 1.3616x over previous
//
#include <hip/hip_runtime.h>
#include <hip/hip_bf16.h>
#include <cstddef>

#define G_   2048
#define NPG_ 512
#define CPG_ 128
#define CPG2_ 32

// output layout (floats): z_what[G,64] | z_mask[G,64] | mu[G,128] | sigma[G,128] | f[G,256]
#define OFF_ZW 0
#define OFF_ZM (G_*64)
#define OFF_MU (2*G_*64)
#define OFF_SG (2*G_*64 + G_*128)
#define OFF_F  (2*G_*64 + 2*G_*128)

typedef __attribute__((ext_vector_type(8))) short bf16x8;
typedef __attribute__((ext_vector_type(4))) float f32x4;
typedef _Float16 f16x2 __attribute__((ext_vector_type(2)));

__device__ __forceinline__ float celu_f(float x)     { return x > 0.f ? x : __expf(x) - 1.f; }
__device__ __forceinline__ float softplus_f(float x) { return fmaxf(x, 0.f) + __logf(1.f + __expf(-fabsf(x))); }
// fast RNE fp32->bf16 (finite inputs): identical result to __float2bfloat16
__device__ __forceinline__ unsigned short f2bf(float x) {
    unsigned u = __float_as_uint(x);
    u += 0x7FFFu + ((u >> 16) & 1u);
    return (unsigned short)(u >> 16);
}
__device__ __forceinline__ unsigned pack2(float a, float b) {   // bf16(a) | bf16(b)<<16
    unsigned ua = __float_as_uint(a); ua += 0x7FFFu + ((ua >> 16) & 1u);
    unsigned ub = __float_as_uint(b); ub += 0x7FFFu + ((ub >> 16) & 1u);
    return (ua >> 16) | (ub & 0xFFFF0000u);
}
// 8B-aligned bf16x8 LDS load (for stride-132/72B rows)
__device__ __forceinline__ bf16x8 ldb8(const unsigned short* p) {
    union { uint2 u[2]; bf16x8 v; } x;
    x.u[0] = *(const uint2*)p;
    x.u[1] = *(const uint2*)(p + 4);
    return x.v;
}

// ---------------- prep: transposed, zero-K-padded bf16 weight copies in ws ----------------
__global__ void k_prep(const float* __restrict__ W2l, const float* __restrict__ W2g,
                       const float* __restrict__ W3l, const float* __restrict__ W3g,
                       const float* __restrict__ Wlin, const float* __restrict__ W1g,
                       unsigned short* __restrict__ w2lT, unsigned short* __restrict__ w2gT,
                       unsigned short* __restrict__ w3lT, unsigned short* __restrict__ w3gT,
                       unsigned short* __restrict__ wlinT, unsigned short* __restrict__ w1gT)
{
    const int tid = blockIdx.x*256 + threadIdx.x, stride = gridDim.x*256;
    for (int i = tid; i < 64*64; i += stride) {          // W2l [35,64] -> [ch][k=64pad]
        const int ch = i >> 6, k = i & 63;
        w2lT[i] = f2bf(k < 35 ? W2l[k*64 + ch] : 0.f);
    }
    for (int i = tid; i < 128*64; i += stride) {         // W2g [64,128] -> [ch][k]
        const int ch = i >> 6, k = i & 63;
        w2gT[i] = f2bf(W2g[k*128 + ch]);
    }
    for (int i = tid; i < 128*160; i += stride) {        // W3l [131,128] -> [ch][k=160pad]
        const int ch = i / 160, k = i % 160;
        w3lT[i] = f2bf(k < 131 ? W3l[k*128 + ch] : 0.f);
    }
    for (int i = tid; i < 256*128; i += stride) {        // W3g [128,256] -> [ch][k]
        const int ch = i >> 7, k = i & 127;
        w3gT[i] = f2bf(W3g[k*256 + ch]);
    }
    for (int i = tid; i < 256*256; i += stride) {        // Wlin [256,256] -> [ch][k]
        const int ch = i >> 8, k = i & 255;
        wlinT[i] = f2bf(Wlin[k*256 + ch]);
    }
    for (int i = tid; i < 32*40; i += stride) {          // W1g [16,32] -> [ch][k=40pad]
        const int ch = i / 40, k = i % 40;
        w1gT[i] = f2bf(k < 16 ? W1g[k*32 + ch] : 0.f);
    }
}

// ============== fused conv1+conv2+conv3local+mean: one block per glimpse ==============
// Sort-based conv1 front-end (round-0 structure), with the edge MLP moved to the
// balanced per-point phase: h[16] computed in f32, packed fp16, scattered to the
// cluster-sorted list; the serial per-cluster loop is a pure v_pk_add_f16 reduction
// split across the 2 owning threads (combine via shfl_xor lane^1).
// LDS 27008 B (6 blocks/CU), overlays:
//  conv1:  spts2 us[512][16] @0 (16384) + aggT us[128][36] @16384 (9216)
//          + cnt/ctr int[128] @25600/@26112 + cnti int[32] @26624 + wtot @26752
//  later:  xs16 us[128][72] @0 -> HT us[64][136] @0 -> xs3 us[32][168] @0
//          sT us[32][132] @18432 -> agg2 us[32][72] -> red f32[128][9]
//  invc f32[32] @26880
__global__ __launch_bounds__(256, 6) void k_fused(
    const float* __restrict__ rgb, const float* __restrict__ pos, const float* __restrict__ pos1,
    const float* __restrict__ pos2, const int* __restrict__ idx0, const int* __restrict__ idx1,
    const float* __restrict__ W1l, const float* __restrict__ b1l,
    const unsigned short* __restrict__ w1gT, const float* __restrict__ b1g,
    const unsigned short* __restrict__ w2lT, const float* __restrict__ b2l,
    const unsigned short* __restrict__ w2gT, const float* __restrict__ b2g,
    const unsigned short* __restrict__ w3lT, const float* __restrict__ b3l,
    unsigned short* __restrict__ aggws)
{
    const int g = blockIdx.x, t = threadIdx.x;
    const int lane = t & 63, wv = t >> 6;
    const int lr = lane & 15, quad = lane >> 4;

    __shared__ __align__(16) unsigned char smem[27008];
    unsigned short* const spts2 = (unsigned short*)smem;            // [512][16] fp16 h
    unsigned short* const aggT  = (unsigned short*)(smem + 16384);  // [128][36]
    unsigned short* const xs16  = (unsigned short*)smem;            // [128][72]
    unsigned short* const HT    = (unsigned short*)smem;            // [64][136]
    unsigned short* const xs3   = (unsigned short*)smem;            // [32][168]
    int* const cnt  = (int*)(smem + 25600);                         // [128]
    int* const ctr  = (int*)(smem + 26112);                         // [128]
    int* const cnti = (int*)(smem + 26624);                         // [32]
    int* const wtot = (int*)(smem + 26752);                         // [1]
    unsigned short* const sT   = (unsigned short*)(smem + 18432);   // [32][132]
    unsigned short* const agg2 = (unsigned short*)(smem + 18432);   // [32][72]
    float* const red  = (float*)(smem + 18432);                     // [128][9]
    float* const invc = (float*)(smem + 26880);                     // [32]

    // ---- pre-B0: counters, slc/rel into regs, zero aggT K-pad cols 16..31, preload w1g ----
    if (t < CPG_)  cnt[t]  = 0;
    if (t < CPG2_) cnti[t] = 0;
    int slc_r = 0;
    float relx = 0.f, rely = 0.f, relz = 0.f;
    if (t < CPG_) {
        const int c2 = idx1[g*CPG_ + t];
        slc_r = c2 - g*CPG2_;
        relx = pos1[(g*CPG_ + t)*3 + 0] - pos2[c2*3 + 0];
        rely = pos1[(g*CPG_ + t)*3 + 1] - pos2[c2*3 + 1];
        relz = pos1[(g*CPG_ + t)*3 + 2] - pos2[c2*3 + 2];
    }
    for (int i = t; i < 128*8; i += 256) {
        const int r = i >> 3, j = i & 7;
        ((unsigned*)aggT)[r*18 + 8 + j] = 0u;
    }
    const bf16x8 w1g_b0 = *(const bf16x8*)&w1gT[(0*16 + lr)*40 + quad*8];
    const bf16x8 w1g_b1 = *(const bf16x8*)&w1gT[(1*16 + lr)*40 + quad*8];
    const float  b1g_0 = b1g[lr], b1g_1 = b1g[16 + lr];
    __syncthreads();   // B0

    // ---- A: load 2 points, per-edge MLP in f32 -> packed fp16 regs, counts ----
    unsigned hpk[2][8];
    int plc[2];
    {
        float px0[2], prx[2], pry[2], prz[2];
        #pragma unroll
        for (int r = 0; r < 2; r++) {
            const int lp = r*256 + t;
            const int p  = g*NPG_ + lp;
            const int c  = idx0[p];
            plc[r] = c - g*CPG_;
            px0[r] = rgb[p];
            prx[r] = pos[p*3+0] - pos1[c*3+0];
            pry[r] = pos[p*3+1] - pos1[c*3+1];
            prz[r] = pos[p*3+2] - pos1[c*3+2];
            atomicAdd(&cnt[plc[r]], 1);
        }
        if (t < CPG_) atomicAdd(&cnti[slc_r], 1);
        #pragma unroll
        for (int j = 0; j < 16; j += 2) {
            const float wj0 = W1l[j],   wx0 = W1l[16+j],   wy0 = W1l[32+j],   wz0 = W1l[48+j],   bb0 = b1l[j];
            const float wj1 = W1l[j+1], wx1 = W1l[16+j+1], wy1 = W1l[32+j+1], wz1 = W1l[48+j+1], bb1 = b1l[j+1];
            #pragma unroll
            for (int r = 0; r < 2; r++) {
                const float h0 = celu_f(bb0 + px0[r]*wj0 + prx[r]*wx0 + pry[r]*wy0 + prz[r]*wz0);
                const float h1 = celu_f(bb1 + px0[r]*wj1 + prx[r]*wx1 + pry[r]*wy1 + prz[r]*wz1);
                union { f16x2 h; unsigned u; } pk;
                pk.h[0] = (_Float16)h0;   // RNE
                pk.h[1] = (_Float16)h1;
                hpk[r][j >> 1] = pk.u;
            }
        }
    }
    __syncthreads();   // B1

    // ---- scan: exclusive base into ctr (race-free cross-wave fixup via wtot) ----
    if (t < CPG_) {
        int val = cnt[t];
        const int ln = t & 63;
        #pragma unroll
        for (int d = 1; d < 64; d <<= 1) {
            const int v = __shfl_up(val, d, 64);
            if (ln >= d) val += v;
        }
        ctr[t] = val - cnt[t];          // exclusive within wave
        if (t == 63) *wtot = val;       // wave-0 total
    }
    __syncthreads();   // B2
    if (t >= 64 && t < CPG_) ctr[t] += *wtot;
    if (t < CPG2_) invc[t] = 1.f / fmaxf((float)cnti[t], 1.f);
    __syncthreads();   // B3

    // ---- C: scatter packed fp16 h into cluster-sorted list ----
    #pragma unroll
    for (int r = 0; r < 2; r++) {
        const int slot = atomicAdd(&ctr[plc[r]], 1);
        uint4 q0, q1;
        q0.x = hpk[r][0]; q0.y = hpk[r][1]; q0.z = hpk[r][2]; q0.w = hpk[r][3];
        q1.x = hpk[r][4]; q1.y = hpk[r][5]; q1.z = hpk[r][6]; q1.w = hpk[r][7];
        *(uint4*)&spts2[slot*16]     = q0;
        *(uint4*)&spts2[slot*16 + 8] = q1;
    }
    __syncthreads();   // B4

    // ---- D: pk_f16 segment reduction, 2 threads/cluster split the list ----
    {
        const int c = t >> 1, half = t & 1;
        const int n = cnt[c];
        const int base = ctr[c] - n;       // ctr[c] == end after scatter
        const int n0 = (n + 1) >> 1;
        const int sI = base + (half ? n0 : 0);
        const int eI = base + (half ? n  : n0);
        f16x2 acc[8];
        #pragma unroll
        for (int j = 0; j < 8; j++) { union { unsigned u; f16x2 h; } z; z.u = 0u; acc[j] = z.h; }
        for (int i = sI; i < eI; i++) {
            const uint4 a = *(const uint4*)&spts2[i*16];
            const uint4 b = *(const uint4*)&spts2[i*16 + 8];
            union { unsigned u; f16x2 h; } w;
            w.u = a.x; acc[0] += w.h;  w.u = a.y; acc[1] += w.h;
            w.u = a.z; acc[2] += w.h;  w.u = a.w; acc[3] += w.h;
            w.u = b.x; acc[4] += w.h;  w.u = b.y; acc[5] += w.h;
            w.u = b.z; acc[6] += w.h;  w.u = b.w; acc[7] += w.h;
        }
        #pragma unroll
        for (int j = 0; j < 8; j++) {      // pair-combine: lanes 2c/2c+1
            union { unsigned u; f16x2 h; } s, o;
            s.h = acc[j];
            o.u = __shfl_xor(s.u, 1);
            acc[j] += o.h;
        }
        const float inv = 1.f / fmaxf((float)n, 1.f);
        const int ch0 = half * 8, j0 = half * 4;
        float v[8];
        #pragma unroll
        for (int k = 0; k < 4; k++) {
            v[2*k]   = (float)acc[j0+k][0] * inv;
            v[2*k+1] = (float)acc[j0+k][1] * inv;
        }
        uint2 q0, q1;
        q0.x = pack2(v[0], v[1]); q0.y = pack2(v[2], v[3]);
        q1.x = pack2(v[4], v[5]); q1.y = pack2(v[6], v[7]);
        *(uint2*)&aggT[c*36 + ch0]     = q0;
        *(uint2*)&aggT[c*36 + ch0 + 4] = q1;
    }
    __syncthreads();   // B5

    // ---- conv1 global conv MFMA: [128,32(K pad)] @ w1gT -> C regs ----
    f32x4 c1[2][2];    // [nt][mt]
    {
        c1[0][0] = (f32x4){b1g_0, b1g_0, b1g_0, b1g_0};
        c1[0][1] = c1[0][0];
        c1[1][0] = (f32x4){b1g_1, b1g_1, b1g_1, b1g_1};
        c1[1][1] = c1[1][0];
        #pragma unroll
        for (int mt = 0; mt < 2; mt++) {
            const bf16x8 a = ldb8(&aggT[((2*wv + mt)*16 + lr)*36 + quad*8]);
            c1[0][mt] = __builtin_amdgcn_mfma_f32_16x16x32_bf16(a, w1g_b0, c1[0][mt], 0, 0, 0);
            c1[1][mt] = __builtin_amdgcn_mfma_f32_16x16x32_bf16(a, w1g_b1, c1[1][mt], 0, 0, 0);
        }
    }
    __syncthreads();   // B6 (spts2/aggT dead -> xs16; cnt/ctr dead -> sT)

    // ---- zero sT; write f1 into xs16 cols 0..31, relpos 32..34, zero 35..63 ----
    {
        const uint4 z4 = {0u, 0u, 0u, 0u};
        for (int i = t; i < 528; i += 256) ((uint4*)sT)[i] = z4;   // 32*132 us = 8448 B
    }
    #pragma unroll
    for (int nt = 0; nt < 2; nt++)
    #pragma unroll
    for (int mt = 0; mt < 2; mt++)
    #pragma unroll
    for (int r = 0; r < 4; r++) {
        const int cl = (2*wv + mt)*16 + quad*4 + r;
        xs16[cl*72 + nt*16 + lr] = f2bf(celu_f(c1[nt][mt][r]));
    }
    if (t < CPG_) {
        xs16[t*72 + 32] = f2bf(relx);
        xs16[t*72 + 33] = f2bf(rely);
        xs16[t*72 + 34] = f2bf(relz);
    }
    for (int i = t; i < 128*29; i += 256) {
        const int r = i / 29, c = 35 + (i - r*29);
        xs16[r*72 + c] = 0;
    }
    __syncthreads();   // B7

    // ---- one-hot scatter into sT; conv2 local MFMA (reads xs16) ----
    if (t < CPG_) sT[slc_r*132 + t] = 0x3F80;   // bf16 1.0
    float hv[8][4];
    {
        const int chn = wv*16 + lr;
        const bf16x8 bw0 = *(const bf16x8*)&w2lT[chn*64 + quad*8];
        const bf16x8 bw1 = *(const bf16x8*)&w2lT[chn*64 + 32 + quad*8];
        const float bias = b2l[chn];
        #pragma unroll
        for (int m = 0; m < 8; m++) {
            f32x4 acc = (f32x4){bias, bias, bias, bias};
            const bf16x8 a0 = *(const bf16x8*)&xs16[(m*16 + lr)*72 + quad*8];
            const bf16x8 a1 = *(const bf16x8*)&xs16[(m*16 + lr)*72 + 32 + quad*8];
            acc = __builtin_amdgcn_mfma_f32_16x16x32_bf16(a0, bw0, acc, 0, 0, 0);
            acc = __builtin_amdgcn_mfma_f32_16x16x32_bf16(a1, bw1, acc, 0, 0, 0);
            #pragma unroll
            for (int r = 0; r < 4; r++) hv[m][r] = celu_f(acc[r]);
        }
    }
    __syncthreads();   // B8 (xs16 dead -> HT)

    // ---- store H^T ----
    {
        const int chn = wv*16 + lr;
        #pragma unroll
        for (int m = 0; m < 8; m++) {
            uint2 p;
            p.x = pack2(hv[m][0], hv[m][1]);
            p.y = pack2(hv[m][2], hv[m][3]);
            *(uint2*)&HT[chn*136 + m*16 + quad*4] = p;
        }
    }
    __syncthreads();   // B9

    // ---- segment-sum MFMA agg[32][64] = S^T @ H (sT rows 8B-aligned -> ldb8) ----
    float aggv[2][4];
    {
        const int ch = wv*16 + lr;
        f32x4 acc[2];
        acc[0] = (f32x4){0.f, 0.f, 0.f, 0.f};
        acc[1] = (f32x4){0.f, 0.f, 0.f, 0.f};
        #pragma unroll
        for (int ks = 0; ks < 4; ks++) {
            const bf16x8 b = *(const bf16x8*)&HT[ch*136 + ks*32 + quad*8];
            #pragma unroll
            for (int mt = 0; mt < 2; mt++) {
                const bf16x8 a = ldb8(&sT[(mt*16 + lr)*132 + ks*32 + quad*8]);
                acc[mt] = __builtin_amdgcn_mfma_f32_16x16x32_bf16(a, b, acc[mt], 0, 0, 0);
            }
        }
        #pragma unroll
        for (int mt = 0; mt < 2; mt++)
        #pragma unroll
        for (int r = 0; r < 4; r++)
            aggv[mt][r] = acc[mt][r] * invc[mt*16 + quad*4 + r];
    }
    __syncthreads();   // B10 (sT dead -> agg2; HT dead -> xs3)

    // ---- agg2 stores (Region2) + xs3 pads/zeros (Region1) ----
    {
        const int ch = wv*16 + lr;
        #pragma unroll
        for (int mt = 0; mt < 2; mt++)
        #pragma unroll
        for (int r = 0; r < 4; r++)
            agg2[(mt*16 + quad*4 + r)*72 + ch] = f2bf(aggv[mt][r]);
    }
    if (t < CPG2_) {
        #pragma unroll
        for (int d = 0; d < 3; d++)
            xs3[t*168 + 128 + d] = f2bf(pos2[(g*CPG2_ + t)*3 + d]);
    }
    for (int i = t; i < 32*29; i += 256) {
        const int r = i / 29, c = 131 + (i - r*29);
        xs3[r*168 + c] = 0;
    }
    __syncthreads();   // B11

    // ---- conv2 global MFMA -> f2 bf16 into xs3 cols 0..127 ----
    {
        f32x4 acc2[2][2];
        int   chn2[2];
        bf16x8 bw[2][2];
        #pragma unroll
        for (int nt = 0; nt < 2; nt++) {
            chn2[nt] = (wv + nt*4)*16 + lr;
            const float bias = b2g[chn2[nt]];
            #pragma unroll
            for (int mt = 0; mt < 2; mt++) acc2[nt][mt] = (f32x4){bias, bias, bias, bias};
            bw[nt][0] = *(const bf16x8*)&w2gT[chn2[nt]*64 + quad*8];
            bw[nt][1] = *(const bf16x8*)&w2gT[chn2[nt]*64 + 32 + quad*8];
        }
        #pragma unroll
        for (int ks = 0; ks < 2; ks++) {
            #pragma unroll
            for (int mt = 0; mt < 2; mt++) {
                const bf16x8 a = *(const bf16x8*)&agg2[(mt*16 + lr)*72 + ks*32 + quad*8];
                acc2[0][mt] = __builtin_amdgcn_mfma_f32_16x16x32_bf16(a, bw[0][ks], acc2[0][mt], 0, 0, 0);
                acc2[1][mt] = __builtin_amdgcn_mfma_f32_16x16x32_bf16(a, bw[1][ks], acc2[1][mt], 0, 0, 0);
            }
        }
        #pragma unroll
        for (int nt = 0; nt < 2; nt++)
        #pragma unroll
        for (int mt = 0; mt < 2; mt++)
        #pragma unroll
        for (int r = 0; r < 4; r++) {
            const int row = mt*16 + quad*4 + r;
            xs3[row*168 + chn2[nt]] = f2bf(celu_f(acc2[nt][mt][r]));
        }
    }
    __syncthreads();   // B12 (agg2 dead -> red)

    // ---- conv3 local MFMA (M=32) -> celu -> partials -> red ----
    {
        f32x4 acc[2][2];
        int chn[2];
        #pragma unroll
        for (int nt = 0; nt < 2; nt++) {
            chn[nt] = (wv + nt*4)*16 + lr;
            const float bias = b3l[chn[nt]];
            #pragma unroll
            for (int mt = 0; mt < 2; mt++) acc[nt][mt] = (f32x4){bias, bias, bias, bias};
        }
        #pragma unroll
        for (int ks = 0; ks < 5; ks++) {
            const bf16x8 b0 = *(const bf16x8*)&w3lT[chn[0]*160 + ks*32 + quad*8];
            const bf16x8 b1 = *(const bf16x8*)&w3lT[chn[1]*160 + ks*32 + quad*8];
            #pragma unroll
            for (int mt = 0; mt < 2; mt++) {
                const bf16x8 a = *(const bf16x8*)&xs3[(mt*16 + lr)*168 + ks*32 + quad*8];
                acc[0][mt] = __builtin_amdgcn_mfma_f32_16x16x32_bf16(a, b0, acc[0][mt], 0, 0, 0);
                acc[1][mt] = __builtin_amdgcn_mfma_f32_16x16x32_bf16(a, b1, acc[1][mt], 0, 0, 0);
            }
        }
        #pragma unroll
        for (int nt = 0; nt < 2; nt++)
        #pragma unroll
        for (int mt = 0; mt < 2; mt++) {
            const float p = celu_f(acc[nt][mt][0]) + celu_f(acc[nt][mt][1])
                          + celu_f(acc[nt][mt][2]) + celu_f(acc[nt][mt][3]);
            red[chn[nt]*9 + mt*4 + quad] = p;
        }
    }
    __syncthreads();   // B13

    // ---- mean -> aggws bf16 ----
    if (t < 128) {
        const float* rp = &red[t*9];
        float a = 0.f;
        #pragma unroll
        for (int p = 0; p < 8; p++) a += rp[p];
        aggws[(size_t)g*128 + t] = f2bf(a * (1.f/32.f));
    }
}

// ============== head: 16 glimpses per block; z/mu/sigma from paired accumulators ==============
__global__ __launch_bounds__(256) void k_head(
    const unsigned short* __restrict__ aggws,
    const unsigned short* __restrict__ w3gT, const float* __restrict__ b3g,
    const unsigned short* __restrict__ wlinT, const float* __restrict__ blin,
    const float* __restrict__ eps, float* __restrict__ out)
{
    const int g0 = blockIdx.x * 16, t = threadIdx.x;
    const int lane = t & 63, wv = t >> 6;
    const int lr = lane & 15, quad = lane >> 4;
    __shared__ __align__(16) unsigned short aggB[16*136];
    __shared__ __align__(16) unsigned short f3B[16*264];

    {   // stage agg rows: 256 uint4
        const int row = t >> 4, col8 = (t & 15) * 8;
        const uint4 v = ((const uint4*)aggws)[(size_t)g0*16 + t];
        *(uint4*)&aggB[row*136 + col8] = v;
    }
    __syncthreads();

    // W3g MFMA: C[16 glimpses][256] = aggB @ W3g
    {
        f32x4 c3[4];
        int ch3[4];
        #pragma unroll
        for (int nt = 0; nt < 4; nt++) {
            ch3[nt] = (wv + nt*4)*16 + lr;
            const float bias = b3g[ch3[nt]];
            c3[nt] = (f32x4){bias, bias, bias, bias};
        }
        #pragma unroll
        for (int ks = 0; ks < 4; ks++) {
            const bf16x8 a = *(const bf16x8*)&aggB[lr*136 + ks*32 + quad*8];
            #pragma unroll
            for (int nt = 0; nt < 4; nt++) {
                const bf16x8 b = *(const bf16x8*)&w3gT[ch3[nt]*128 + ks*32 + quad*8];
                c3[nt] = __builtin_amdgcn_mfma_f32_16x16x32_bf16(a, b, c3[nt], 0, 0, 0);
            }
        }
        #pragma unroll
        for (int nt = 0; nt < 4; nt++)
        #pragma unroll
        for (int r = 0; r < 4; r++) {
            const int row = quad*4 + r;
            const float v = celu_f(c3[nt][r]);
            out[OFF_F + (size_t)(g0 + row)*256 + ch3[nt]] = v;
            f3B[row*264 + ch3[nt]] = f2bf(v);
        }
    }
    __syncthreads();

    // Wlin MFMA: C[16][256] = f3B @ Wlin; sample in-register (lane owns ch and ch+128)
    {
        f32x4 cl[4];
        int ch4[4];
        #pragma unroll
        for (int nt = 0; nt < 4; nt++) {
            ch4[nt] = (wv + nt*4)*16 + lr;
            const float bias = blin[ch4[nt]];
            cl[nt] = (f32x4){bias, bias, bias, bias};
        }
        #pragma unroll
        for (int ks = 0; ks < 8; ks++) {
            const bf16x8 a = *(const bf16x8*)&f3B[lr*264 + ks*32 + quad*8];
            #pragma unroll
            for (int nt = 0; nt < 4; nt++) {
                const bf16x8 b = *(const bf16x8*)&wlinT[ch4[nt]*256 + ks*32 + quad*8];
                cl[nt] = __builtin_amdgcn_mfma_f32_16x16x32_bf16(a, b, cl[nt], 0, 0, 0);
            }
        }
        // nt and nt+2 share the lane: ch4[nt+2] == ch4[nt] + 128
        #pragma unroll
        for (int nt = 0; nt < 2; nt++)
        #pragma unroll
        for (int r = 0; r < 4; r++) {
            const int row = quad*4 + r;
            const int g = g0 + row;
            const int ch = ch4[nt];                 // 0..127
            const float mu    = cl[nt][r];
            const float sigma = softplus_f(cl[nt + 2][r]);
            const float z     = mu + sigma * eps[(size_t)g*128 + ch];
            out[OFF_MU + (size_t)g*128 + ch] = mu;
            out[OFF_SG + (size_t)g*128 + ch] = sigma;
            if (nt == 0) out[OFF_ZW + (size_t)g*64 + ch] = z;          // ch in [0,64)
            else         out[OFF_ZM + (size_t)g*64 + (ch - 64)] = z;   // ch in [64,128)
        }
    }
}

extern "C" void kernel_launch(void* const* d_in, const int* in_sizes, int n_in,
                              void* d_out, int out_size, void* d_ws, size_t ws_size,
                              hipStream_t stream)
{
    const float* rgb  = (const float*)d_in[0];
    const float* pos  = (const float*)d_in[1];
    const float* pos1 = (const float*)d_in[2];
    const float* pos2 = (const float*)d_in[3];
    const int*   idx0 = (const int*)d_in[4];
    const int*   idx1 = (const int*)d_in[5];
    const float* eps  = (const float*)d_in[7];
    const float* W1l = (const float*)d_in[8],  *b1l = (const float*)d_in[9];
    const float* W1g = (const float*)d_in[10], *b1g = (const float*)d_in[11];
    const float* W2l = (const float*)d_in[12], *b2l = (const float*)d_in[13];
    const float* W2g = (const float*)d_in[14], *b2g = (const float*)d_in[15];
    const float* W3l = (const float*)d_in[16], *b3l = (const float*)d_in[17];
    const float* W3g = (const float*)d_in[18], *b3g = (const float*)d_in[19];
    const float* Wlin = (const float*)d_in[20], *blin = (const float*)d_in[21];

    unsigned short* w2lT  = (unsigned short*)d_ws;       // 64*64
    unsigned short* w2gT  = w2lT + 64*64;                // 128*64
    unsigned short* w3lT  = w2gT + 128*64;               // 128*160
    unsigned short* w3gT  = w3lT + 128*160;              // 256*128
    unsigned short* wlinT = w3gT + 256*128;              // 256*256
    unsigned short* w1gT  = wlinT + 256*256;             // 32*40
    unsigned short* aggws = w1gT + 32*40;                // G*128 bf16
    float* outp = (float*)d_out;

    k_prep <<<64,    256, 0, stream>>>(W2l, W2g, W3l, W3g, Wlin, W1g,
                                       w2lT, w2gT, w3lT, w3gT, wlinT, w1gT);
    k_fused<<<G_,    256, 0, stream>>>(rgb, pos, pos1, pos2, idx0, idx1,
                                       W1l, b1l, w1gT, b1g,
                                       w2lT, b2l, w2gT, b2g, w3lT, b3l, aggws);
    k_head <<<G_/16, 256, 0, stream>>>(aggws, w3gT, b3g, wlinT, blin, eps, outp);
}

// Round 3
// 156.578 us; speedup vs baseline: 1.4650x; 1.0759x over previous
//
#include <hip/hip_runtime.h>
#include <hip/hip_bf16.h>
#include <cstddef>

#define G_   2048
#define NPG_ 512
#define CPG_ 128
#define CPG2_ 32

// output layout (floats): z_what[G,64] | z_mask[G,64] | mu[G,128] | sigma[G,128] | f[G,256]
#define OFF_ZW 0
#define OFF_ZM (G_*64)
#define OFF_MU (2*G_*64)
#define OFF_SG (2*G_*64 + G_*128)
#define OFF_F  (2*G_*64 + 2*G_*128)

typedef __attribute__((ext_vector_type(8))) short bf16x8;
typedef __attribute__((ext_vector_type(4))) float f32x4;
typedef _Float16 f16x2 __attribute__((ext_vector_type(2)));

__device__ __forceinline__ float celu_f(float x)     { return x > 0.f ? x : __expf(x) - 1.f; }
__device__ __forceinline__ float softplus_f(float x) { return fmaxf(x, 0.f) + __logf(1.f + __expf(-fabsf(x))); }
// fast RNE fp32->bf16 (finite inputs): identical result to __float2bfloat16
__device__ __forceinline__ unsigned short f2bf(float x) {
    unsigned u = __float_as_uint(x);
    u += 0x7FFFu + ((u >> 16) & 1u);
    return (unsigned short)(u >> 16);
}
__device__ __forceinline__ unsigned pack2(float a, float b) {   // bf16(a) | bf16(b)<<16
    unsigned ua = __float_as_uint(a); ua += 0x7FFFu + ((ua >> 16) & 1u);
    unsigned ub = __float_as_uint(b); ub += 0x7FFFu + ((ub >> 16) & 1u);
    return (ua >> 16) | (ub & 0xFFFF0000u);
}
// 8B-aligned bf16x8 LDS load (for stride-132/72B rows)
__device__ __forceinline__ bf16x8 ldb8(const unsigned short* p) {
    union { uint2 u[2]; bf16x8 v; } x;
    x.u[0] = *(const uint2*)p;
    x.u[1] = *(const uint2*)(p + 4);
    return x.v;
}

// ---------------- prep: transposed, zero-K-padded bf16 weight copies in ws ----------------
__global__ void k_prep(const float* __restrict__ W2l, const float* __restrict__ W2g,
                       const float* __restrict__ W3l, const float* __restrict__ W3g,
                       const float* __restrict__ Wlin, const float* __restrict__ W1g,
                       unsigned short* __restrict__ w2lT, unsigned short* __restrict__ w2gT,
                       unsigned short* __restrict__ w3lT, unsigned short* __restrict__ w3gT,
                       unsigned short* __restrict__ wlinT, unsigned short* __restrict__ w1gT)
{
    const int tid = blockIdx.x*256 + threadIdx.x, stride = gridDim.x*256;
    for (int i = tid; i < 64*64; i += stride) {          // W2l [35,64] -> [ch][k=64pad]
        const int ch = i >> 6, k = i & 63;
        w2lT[i] = f2bf(k < 35 ? W2l[k*64 + ch] : 0.f);
    }
    for (int i = tid; i < 128*64; i += stride) {         // W2g [64,128] -> [ch][k]
        const int ch = i >> 6, k = i & 63;
        w2gT[i] = f2bf(W2g[k*128 + ch]);
    }
    for (int i = tid; i < 128*160; i += stride) {        // W3l [131,128] -> [ch][k=160pad]
        const int ch = i / 160, k = i % 160;
        w3lT[i] = f2bf(k < 131 ? W3l[k*128 + ch] : 0.f);
    }
    for (int i = tid; i < 256*128; i += stride) {        // W3g [128,256] -> [ch][k]
        const int ch = i >> 7, k = i & 127;
        w3gT[i] = f2bf(W3g[k*256 + ch]);
    }
    for (int i = tid; i < 256*256; i += stride) {        // Wlin [256,256] -> [ch][k]
        const int ch = i >> 8, k = i & 255;
        wlinT[i] = f2bf(Wlin[k*256 + ch]);
    }
    for (int i = tid; i < 32*40; i += stride) {          // W1g [16,32] -> [ch][k=40pad]
        const int ch = i / 40, k = i % 40;
        w1gT[i] = f2bf(k < 16 ? W1g[k*32 + ch] : 0.f);
    }
}

// ============== fused conv1+conv2+conv3local+mean: one block per glimpse ==============
// conv1 front-end: balanced per-point MLP computed AFTER the scan (no big reg state
// across barriers -> no spill), scattered as packed fp16 into 8 SoA channel-planes
// u32[8][512] (bank = slot%32 -> ~2-way random collisions, free per m136). Serial
// per-cluster reduce is pure v_pk_add_f16, split across the 2 owning threads.
// LDS 27008 B (6 blocks/CU), overlays:
//  conv1:  hplanes u32[8][512] @0 (16384) + aggT us[128][36] @16384 (9216)
//          + cnt/ctr int[128] @25600/@26112 + cnti int[32] @26624 + wtot @26752
//  later:  xs16 us[128][72] @0 -> HT us[64][136] @0 -> xs3 us[32][168] @0
//          sT us[32][132] @18432 -> agg2 us[32][72] -> red f32[128][9]
//  invc f32[32] @26880
__global__ __launch_bounds__(256, 6) void k_fused(
    const float* __restrict__ rgb, const float* __restrict__ pos, const float* __restrict__ pos1,
    const float* __restrict__ pos2, const int* __restrict__ idx0, const int* __restrict__ idx1,
    const float* __restrict__ W1l, const float* __restrict__ b1l,
    const unsigned short* __restrict__ w1gT, const float* __restrict__ b1g,
    const unsigned short* __restrict__ w2lT, const float* __restrict__ b2l,
    const unsigned short* __restrict__ w2gT, const float* __restrict__ b2g,
    const unsigned short* __restrict__ w3lT, const float* __restrict__ b3l,
    unsigned short* __restrict__ aggws)
{
    const int g = blockIdx.x, t = threadIdx.x;
    const int lane = t & 63, wv = t >> 6;
    const int lr = lane & 15, quad = lane >> 4;

    __shared__ __align__(16) unsigned char smem[27008];
    unsigned* const hplanes = (unsigned*)smem;                      // [8][512] u32 (2 fp16 ch each)
    unsigned short* const aggT  = (unsigned short*)(smem + 16384);  // [128][36]
    unsigned short* const xs16  = (unsigned short*)smem;            // [128][72]
    unsigned short* const HT    = (unsigned short*)smem;            // [64][136]
    unsigned short* const xs3   = (unsigned short*)smem;            // [32][168]
    int* const cnt  = (int*)(smem + 25600);                         // [128]
    int* const ctr  = (int*)(smem + 26112);                         // [128]
    int* const cnti = (int*)(smem + 26624);                         // [32]
    int* const wtot = (int*)(smem + 26752);                         // [1]
    unsigned short* const sT   = (unsigned short*)(smem + 18432);   // [32][132]
    unsigned short* const agg2 = (unsigned short*)(smem + 18432);   // [32][72]
    float* const red  = (float*)(smem + 18432);                     // [128][9]
    float* const invc = (float*)(smem + 26880);                     // [32]

    // ---- pre-B0: counters, slc/rel into regs, zero aggT K-pad cols 16..31 ----
    if (t < CPG_)  cnt[t]  = 0;
    if (t < CPG2_) cnti[t] = 0;
    int slc_r = 0;
    float relx = 0.f, rely = 0.f, relz = 0.f;
    if (t < CPG_) {
        const int c2 = idx1[g*CPG_ + t];
        slc_r = c2 - g*CPG2_;
        relx = pos1[(g*CPG_ + t)*3 + 0] - pos2[c2*3 + 0];
        rely = pos1[(g*CPG_ + t)*3 + 1] - pos2[c2*3 + 1];
        relz = pos1[(g*CPG_ + t)*3 + 2] - pos2[c2*3 + 2];
    }
    for (int i = t; i < 128*8; i += 256) {
        const int r = i >> 3, j = i & 7;
        ((unsigned*)aggT)[r*18 + 8 + j] = 0u;
    }
    __syncthreads();   // B0

    // ---- A: load 2 points raw (regs: 8 floats + 2 ints across scan) + counts ----
    float px0[2], prx[2], pry[2], prz[2];
    int plc[2];
    #pragma unroll
    for (int r = 0; r < 2; r++) {
        const int lp = r*256 + t;
        const int p  = g*NPG_ + lp;
        const int c  = idx0[p];
        plc[r] = c - g*CPG_;
        px0[r] = rgb[p];
        prx[r] = pos[p*3+0] - pos1[c*3+0];
        pry[r] = pos[p*3+1] - pos1[c*3+1];
        prz[r] = pos[p*3+2] - pos1[c*3+2];
        atomicAdd(&cnt[plc[r]], 1);
    }
    if (t < CPG_) atomicAdd(&cnti[slc_r], 1);
    __syncthreads();   // B1

    // ---- scan: exclusive base into ctr (race-free cross-wave fixup via wtot) ----
    if (t < CPG_) {
        int val = cnt[t];
        const int ln = t & 63;
        #pragma unroll
        for (int d = 1; d < 64; d <<= 1) {
            const int v = __shfl_up(val, d, 64);
            if (ln >= d) val += v;
        }
        ctr[t] = val - cnt[t];          // exclusive within wave
        if (t == 63) *wtot = val;       // wave-0 total
    }
    __syncthreads();   // B2
    if (t >= 64 && t < CPG_) ctr[t] += *wtot;
    if (t < CPG2_) invc[t] = 1.f / fmaxf((float)cnti[t], 1.f);
    __syncthreads();   // B3

    // ---- C: per-point MLP in f32 -> packed fp16 -> SoA plane scatter ----
    #pragma unroll
    for (int r = 0; r < 2; r++) {
        unsigned hpk[8];
        #pragma unroll
        for (int j = 0; j < 16; j += 2) {
            const float h0 = celu_f(b1l[j]   + px0[r]*W1l[j]   + prx[r]*W1l[16+j]
                                              + pry[r]*W1l[32+j]   + prz[r]*W1l[48+j]);
            const float h1 = celu_f(b1l[j+1] + px0[r]*W1l[j+1] + prx[r]*W1l[16+j+1]
                                              + pry[r]*W1l[32+j+1] + prz[r]*W1l[48+j+1]);
            union { f16x2 h; unsigned u; } pk;
            pk.h[0] = (_Float16)h0;   // RNE
            pk.h[1] = (_Float16)h1;
            hpk[j >> 1] = pk.u;
        }
        const int slot = atomicAdd(&ctr[plc[r]], 1);
        #pragma unroll
        for (int j = 0; j < 8; j++) hplanes[j*512 + slot] = hpk[j];
    }
    __syncthreads();   // B4

    // issue w1g fragment loads now: latency hides under the serial reduce
    const bf16x8 w1g_b0 = *(const bf16x8*)&w1gT[lr*40 + quad*8];
    const bf16x8 w1g_b1 = *(const bf16x8*)&w1gT[(16 + lr)*40 + quad*8];
    const float  b1g_0 = b1g[lr], b1g_1 = b1g[16 + lr];

    // ---- D: pk_f16 segment reduction, 2 threads/cluster split the list ----
    {
        const int c = t >> 1, half = t & 1;
        const int n = cnt[c];
        const int base = ctr[c] - n;       // ctr[c] == end after scatter
        const int n0 = (n + 1) >> 1;
        const int sI = base + (half ? n0 : 0);
        const int eI = base + (half ? n  : n0);
        f16x2 acc[8];
        #pragma unroll
        for (int j = 0; j < 8; j++) { union { unsigned u; f16x2 h; } z; z.u = 0u; acc[j] = z.h; }
        for (int i = sI; i < eI; i++) {
            #pragma unroll
            for (int j = 0; j < 8; j++) {
                union { unsigned u; f16x2 h; } w;
                w.u = hplanes[j*512 + i];
                acc[j] += w.h;
            }
        }
        #pragma unroll
        for (int j = 0; j < 8; j++) {      // pair-combine: lanes 2c/2c+1
            union { unsigned u; f16x2 h; } s, o;
            s.h = acc[j];
            o.u = __shfl_xor(s.u, 1);
            acc[j] += o.h;
        }
        const float inv = 1.f / fmaxf((float)n, 1.f);
        const int ch0 = half * 8, j0 = half * 4;
        float v[8];
        #pragma unroll
        for (int k = 0; k < 4; k++) {
            v[2*k]   = (float)acc[j0+k][0] * inv;
            v[2*k+1] = (float)acc[j0+k][1] * inv;
        }
        uint2 q0, q1;
        q0.x = pack2(v[0], v[1]); q0.y = pack2(v[2], v[3]);
        q1.x = pack2(v[4], v[5]); q1.y = pack2(v[6], v[7]);
        *(uint2*)&aggT[c*36 + ch0]     = q0;
        *(uint2*)&aggT[c*36 + ch0 + 4] = q1;
    }
    __syncthreads();   // B5

    // ---- conv1 global conv MFMA: [128,32(K pad)] @ w1gT -> C regs ----
    f32x4 c1[2][2];    // [nt][mt]
    {
        c1[0][0] = (f32x4){b1g_0, b1g_0, b1g_0, b1g_0};
        c1[0][1] = c1[0][0];
        c1[1][0] = (f32x4){b1g_1, b1g_1, b1g_1, b1g_1};
        c1[1][1] = c1[1][0];
        #pragma unroll
        for (int mt = 0; mt < 2; mt++) {
            const bf16x8 a = ldb8(&aggT[((2*wv + mt)*16 + lr)*36 + quad*8]);
            c1[0][mt] = __builtin_amdgcn_mfma_f32_16x16x32_bf16(a, w1g_b0, c1[0][mt], 0, 0, 0);
            c1[1][mt] = __builtin_amdgcn_mfma_f32_16x16x32_bf16(a, w1g_b1, c1[1][mt], 0, 0, 0);
        }
    }
    __syncthreads();   // B6 (hplanes/aggT dead -> xs16; cnt/ctr dead -> sT)

    // ---- zero sT; write f1 into xs16 cols 0..31, relpos 32..34, zero 35..63 ----
    {
        const uint4 z4 = {0u, 0u, 0u, 0u};
        for (int i = t; i < 528; i += 256) ((uint4*)sT)[i] = z4;   // 32*132 us = 8448 B
    }
    #pragma unroll
    for (int nt = 0; nt < 2; nt++)
    #pragma unroll
    for (int mt = 0; mt < 2; mt++)
    #pragma unroll
    for (int r = 0; r < 4; r++) {
        const int cl = (2*wv + mt)*16 + quad*4 + r;
        xs16[cl*72 + nt*16 + lr] = f2bf(celu_f(c1[nt][mt][r]));
    }
    if (t < CPG_) {
        xs16[t*72 + 32] = f2bf(relx);
        xs16[t*72 + 33] = f2bf(rely);
        xs16[t*72 + 34] = f2bf(relz);
    }
    for (int i = t; i < 128*29; i += 256) {
        const int r = i / 29, c = 35 + (i - r*29);
        xs16[r*72 + c] = 0;
    }
    __syncthreads();   // B7

    // ---- one-hot scatter into sT; conv2 local MFMA (reads xs16) ----
    if (t < CPG_) sT[slc_r*132 + t] = 0x3F80;   // bf16 1.0
    float hv[8][4];
    {
        const int chn = wv*16 + lr;
        const bf16x8 bw0 = *(const bf16x8*)&w2lT[chn*64 + quad*8];
        const bf16x8 bw1 = *(const bf16x8*)&w2lT[chn*64 + 32 + quad*8];
        const float bias = b2l[chn];
        #pragma unroll
        for (int m = 0; m < 8; m++) {
            f32x4 acc = (f32x4){bias, bias, bias, bias};
            const bf16x8 a0 = *(const bf16x8*)&xs16[(m*16 + lr)*72 + quad*8];
            const bf16x8 a1 = *(const bf16x8*)&xs16[(m*16 + lr)*72 + 32 + quad*8];
            acc = __builtin_amdgcn_mfma_f32_16x16x32_bf16(a0, bw0, acc, 0, 0, 0);
            acc = __builtin_amdgcn_mfma_f32_16x16x32_bf16(a1, bw1, acc, 0, 0, 0);
            #pragma unroll
            for (int r = 0; r < 4; r++) hv[m][r] = celu_f(acc[r]);
        }
    }
    __syncthreads();   // B8 (xs16 dead -> HT)

    // ---- store H^T ----
    {
        const int chn = wv*16 + lr;
        #pragma unroll
        for (int m = 0; m < 8; m++) {
            uint2 p;
            p.x = pack2(hv[m][0], hv[m][1]);
            p.y = pack2(hv[m][2], hv[m][3]);
            *(uint2*)&HT[chn*136 + m*16 + quad*4] = p;
        }
    }
    __syncthreads();   // B9

    // ---- segment-sum MFMA agg[32][64] = S^T @ H (sT rows 8B-aligned -> ldb8) ----
    float aggv[2][4];
    {
        const int ch = wv*16 + lr;
        f32x4 acc[2];
        acc[0] = (f32x4){0.f, 0.f, 0.f, 0.f};
        acc[1] = (f32x4){0.f, 0.f, 0.f, 0.f};
        #pragma unroll
        for (int ks = 0; ks < 4; ks++) {
            const bf16x8 b = *(const bf16x8*)&HT[ch*136 + ks*32 + quad*8];
            #pragma unroll
            for (int mt = 0; mt < 2; mt++) {
                const bf16x8 a = ldb8(&sT[(mt*16 + lr)*132 + ks*32 + quad*8]);
                acc[mt] = __builtin_amdgcn_mfma_f32_16x16x32_bf16(a, b, acc[mt], 0, 0, 0);
            }
        }
        #pragma unroll
        for (int mt = 0; mt < 2; mt++)
        #pragma unroll
        for (int r = 0; r < 4; r++)
            aggv[mt][r] = acc[mt][r] * invc[mt*16 + quad*4 + r];
    }
    __syncthreads();   // B10 (sT dead -> agg2; HT dead -> xs3)

    // ---- agg2 stores (Region2) + xs3 pads/zeros (Region1) ----
    {
        const int ch = wv*16 + lr;
        #pragma unroll
        for (int mt = 0; mt < 2; mt++)
        #pragma unroll
        for (int r = 0; r < 4; r++)
            agg2[(mt*16 + quad*4 + r)*72 + ch] = f2bf(aggv[mt][r]);
    }
    if (t < CPG2_) {
        #pragma unroll
        for (int d = 0; d < 3; d++)
            xs3[t*168 + 128 + d] = f2bf(pos2[(g*CPG2_ + t)*3 + d]);
    }
    for (int i = t; i < 32*29; i += 256) {
        const int r = i / 29, c = 131 + (i - r*29);
        xs3[r*168 + c] = 0;
    }
    __syncthreads();   // B11

    // ---- conv2 global MFMA -> f2 bf16 into xs3 cols 0..127 ----
    {
        f32x4 acc2[2][2];
        int   chn2[2];
        bf16x8 bw[2][2];
        #pragma unroll
        for (int nt = 0; nt < 2; nt++) {
            chn2[nt] = (wv + nt*4)*16 + lr;
            const float bias = b2g[chn2[nt]];
            #pragma unroll
            for (int mt = 0; mt < 2; mt++) acc2[nt][mt] = (f32x4){bias, bias, bias, bias};
            bw[nt][0] = *(const bf16x8*)&w2gT[chn2[nt]*64 + quad*8];
            bw[nt][1] = *(const bf16x8*)&w2gT[chn2[nt]*64 + 32 + quad*8];
        }
        #pragma unroll
        for (int ks = 0; ks < 2; ks++) {
            #pragma unroll
            for (int mt = 0; mt < 2; mt++) {
                const bf16x8 a = *(const bf16x8*)&agg2[(mt*16 + lr)*72 + ks*32 + quad*8];
                acc2[0][mt] = __builtin_amdgcn_mfma_f32_16x16x32_bf16(a, bw[0][ks], acc2[0][mt], 0, 0, 0);
                acc2[1][mt] = __builtin_amdgcn_mfma_f32_16x16x32_bf16(a, bw[1][ks], acc2[1][mt], 0, 0, 0);
            }
        }
        #pragma unroll
        for (int nt = 0; nt < 2; nt++)
        #pragma unroll
        for (int mt = 0; mt < 2; mt++)
        #pragma unroll
        for (int r = 0; r < 4; r++) {
            const int row = mt*16 + quad*4 + r;
            xs3[row*168 + chn2[nt]] = f2bf(celu_f(acc2[nt][mt][r]));
        }
    }
    __syncthreads();   // B12 (agg2 dead -> red)

    // ---- conv3 local MFMA (M=32) -> celu -> partials -> red ----
    {
        f32x4 acc[2][2];
        int chn[2];
        #pragma unroll
        for (int nt = 0; nt < 2; nt++) {
            chn[nt] = (wv + nt*4)*16 + lr;
            const float bias = b3l[chn[nt]];
            #pragma unroll
            for (int mt = 0; mt < 2; mt++) acc[nt][mt] = (f32x4){bias, bias, bias, bias};
        }
        #pragma unroll
        for (int ks = 0; ks < 5; ks++) {
            const bf16x8 b0 = *(const bf16x8*)&w3lT[chn[0]*160 + ks*32 + quad*8];
            const bf16x8 b1 = *(const bf16x8*)&w3lT[chn[1]*160 + ks*32 + quad*8];
            #pragma unroll
            for (int mt = 0; mt < 2; mt++) {
                const bf16x8 a = *(const bf16x8*)&xs3[(mt*16 + lr)*168 + ks*32 + quad*8];
                acc[0][mt] = __builtin_amdgcn_mfma_f32_16x16x32_bf16(a, b0, acc[0][mt], 0, 0, 0);
                acc[1][mt] = __builtin_amdgcn_mfma_f32_16x16x32_bf16(a, b1, acc[1][mt], 0, 0, 0);
            }
        }
        #pragma unroll
        for (int nt = 0; nt < 2; nt++)
        #pragma unroll
        for (int mt = 0; mt < 2; mt++) {
            const float p = celu_f(acc[nt][mt][0]) + celu_f(acc[nt][mt][1])
                          + celu_f(acc[nt][mt][2]) + celu_f(acc[nt][mt][3]);
            red[chn[nt]*9 + mt*4 + quad] = p;
        }
    }
    __syncthreads();   // B13

    // ---- mean -> aggws bf16 ----
    if (t < 128) {
        const float* rp = &red[t*9];
        float a = 0.f;
        #pragma unroll
        for (int p = 0; p < 8; p++) a += rp[p];
        aggws[(size_t)g*128 + t] = f2bf(a * (1.f/32.f));
    }
}

// ============== head: 16 glimpses per block; z/mu/sigma from paired accumulators ==============
__global__ __launch_bounds__(256) void k_head(
    const unsigned short* __restrict__ aggws,
    const unsigned short* __restrict__ w3gT, const float* __restrict__ b3g,
    const unsigned short* __restrict__ wlinT, const float* __restrict__ blin,
    const float* __restrict__ eps, float* __restrict__ out)
{
    const int g0 = blockIdx.x * 16, t = threadIdx.x;
    const int lane = t & 63, wv = t >> 6;
    const int lr = lane & 15, quad = lane >> 4;
    __shared__ __align__(16) unsigned short aggB[16*136];
    __shared__ __align__(16) unsigned short f3B[16*264];

    {   // stage agg rows: 256 uint4
        const int row = t >> 4, col8 = (t & 15) * 8;
        const uint4 v = ((const uint4*)aggws)[(size_t)g0*16 + t];
        *(uint4*)&aggB[row*136 + col8] = v;
    }
    __syncthreads();

    // W3g MFMA: C[16 glimpses][256] = aggB @ W3g
    {
        f32x4 c3[4];
        int ch3[4];
        #pragma unroll
        for (int nt = 0; nt < 4; nt++) {
            ch3[nt] = (wv + nt*4)*16 + lr;
            const float bias = b3g[ch3[nt]];
            c3[nt] = (f32x4){bias, bias, bias, bias};
        }
        #pragma unroll
        for (int ks = 0; ks < 4; ks++) {
            const bf16x8 a = *(const bf16x8*)&aggB[lr*136 + ks*32 + quad*8];
            #pragma unroll
            for (int nt = 0; nt < 4; nt++) {
                const bf16x8 b = *(const bf16x8*)&w3gT[ch3[nt]*128 + ks*32 + quad*8];
                c3[nt] = __builtin_amdgcn_mfma_f32_16x16x32_bf16(a, b, c3[nt], 0, 0, 0);
            }
        }
        #pragma unroll
        for (int nt = 0; nt < 4; nt++)
        #pragma unroll
        for (int r = 0; r < 4; r++) {
            const int row = quad*4 + r;
            const float v = celu_f(c3[nt][r]);
            out[OFF_F + (size_t)(g0 + row)*256 + ch3[nt]] = v;
            f3B[row*264 + ch3[nt]] = f2bf(v);
        }
    }
    __syncthreads();

    // Wlin MFMA: C[16][256] = f3B @ Wlin; sample in-register (lane owns ch and ch+128)
    {
        f32x4 cl[4];
        int ch4[4];
        #pragma unroll
        for (int nt = 0; nt < 4; nt++) {
            ch4[nt] = (wv + nt*4)*16 + lr;
            const float bias = blin[ch4[nt]];
            cl[nt] = (f32x4){bias, bias, bias, bias};
        }
        #pragma unroll
        for (int ks = 0; ks < 8; ks++) {
            const bf16x8 a = *(const bf16x8*)&f3B[lr*264 + ks*32 + quad*8];
            #pragma unroll
            for (int nt = 0; nt < 4; nt++) {
                const bf16x8 b = *(const bf16x8*)&wlinT[ch4[nt]*256 + ks*32 + quad*8];
                cl[nt] = __builtin_amdgcn_mfma_f32_16x16x32_bf16(a, b, cl[nt], 0, 0, 0);
            }
        }
        // nt and nt+2 share the lane: ch4[nt+2] == ch4[nt] + 128
        #pragma unroll
        for (int nt = 0; nt < 2; nt++)
        #pragma unroll
        for (int r = 0; r < 4; r++) {
            const int row = quad*4 + r;
            const int g = g0 + row;
            const int ch = ch4[nt];                 // 0..127
            const float mu    = cl[nt][r];
            const float sigma = softplus_f(cl[nt + 2][r]);
            const float z     = mu + sigma * eps[(size_t)g*128 + ch];
            out[OFF_MU + (size_t)g*128 + ch] = mu;
            out[OFF_SG + (size_t)g*128 + ch] = sigma;
            if (nt == 0) out[OFF_ZW + (size_t)g*64 + ch] = z;          // ch in [0,64)
            else         out[OFF_ZM + (size_t)g*64 + (ch - 64)] = z;   // ch in [64,128)
        }
    }
}

extern "C" void kernel_launch(void* const* d_in, const int* in_sizes, int n_in,
                              void* d_out, int out_size, void* d_ws, size_t ws_size,
                              hipStream_t stream)
{
    const float* rgb  = (const float*)d_in[0];
    const float* pos  = (const float*)d_in[1];
    const float* pos1 = (const float*)d_in[2];
    const float* pos2 = (const float*)d_in[3];
    const int*   idx0 = (const int*)d_in[4];
    const int*   idx1 = (const int*)d_in[5];
    const float* eps  = (const float*)d_in[7];
    const float* W1l = (const float*)d_in[8],  *b1l = (const float*)d_in[9];
    const float* W1g = (const float*)d_in[10], *b1g = (const float*)d_in[11];
    const float* W2l = (const float*)d_in[12], *b2l = (const float*)d_in[13];
    const float* W2g = (const float*)d_in[14], *b2g = (const float*)d_in[15];
    const float* W3l = (const float*)d_in[16], *b3l = (const float*)d_in[17];
    const float* W3g = (const float*)d_in[18], *b3g = (const float*)d_in[19];
    const float* Wlin = (const float*)d_in[20], *blin = (const float*)d_in[21];

    unsigned short* w2lT  = (unsigned short*)d_ws;       // 64*64
    unsigned short* w2gT  = w2lT + 64*64;                // 128*64
    unsigned short* w3lT  = w2gT + 128*64;               // 128*160
    unsigned short* w3gT  = w3lT + 128*160;              // 256*128
    unsigned short* wlinT = w3gT + 256*128;              // 256*256
    unsigned short* w1gT  = wlinT + 256*256;             // 32*40
    unsigned short* aggws = w1gT + 32*40;                // G*128 bf16
    float* outp = (float*)d_out;

    k_prep <<<64,    256, 0, stream>>>(W2l, W2g, W3l, W3g, Wlin, W1g,
                                       w2lT, w2gT, w3lT, w3gT, wlinT, w1gT);
    k_fused<<<G_,    256, 0, stream>>>(rgb, pos, pos1, pos2, idx0, idx1,
                                       W1l, b1l, w1gT, b1g,
                                       w2lT, b2l, w2gT, b2g, w3lT, b3l, aggws);
    k_head <<<G_/16, 256, 0, stream>>>(aggws, w3gT, b3g, wlinT, blin, eps, outp);
}